// Round 8
// baseline (184.517 us; speedup 1.0000x reference)
//
#include <hip/hip_runtime.h>
#include <hip/hip_bf16.h>

// MultiEdgeTypePredictor — R5: per-node projection restructure.
//
//   GEMM1 is linear before ReLU:  x[e] = relu(Psrc[s[e]] + Pdst[d[e]] + b1)
//   with Psrc = h_src @ W1[:256,:], Pdst = h_dst @ W1[256:,:].
//
//   prep_kernel : pack W1/W2 MFMA B-frags (bf16) + fold BN+emb into sc/sh.
//   proj_kernel : dense streaming GEMM  h -> P (bf16, in d_ws). 205MB seq read.
//   edge_kernel : gather P rows (512B/edge vs 2KB before), add+ReLU+BN+emb,
//                 GEMM2 (MFMA) + GEMM3 (shfl reduce).
//
//   Fallback: if ws_size can't hold P (~51.3MB), run the R4 fused path.

typedef __attribute__((ext_vector_type(8))) short bf16x8;
typedef __attribute__((ext_vector_type(4))) float f32x4;
typedef __attribute__((ext_vector_type(8))) unsigned short u16x8;

constexpr int HID   = 128;
constexpr int ETILE = 64;
constexpr int AS    = 72;    // R4 chunk-buffer row stride (bf16 elems)
constexpr int XS    = 136;   // x-tile row stride (bf16 elems, 272B)

__device__ inline ushort f2bf(float f) {
    union { __hip_bfloat16 h; ushort u; } cv;
    cv.h = __float2bfloat16(f);   // RNE
    return cv.u;
}
__device__ inline float bf2f(ushort u) {
    return __uint_as_float(((unsigned int)u) << 16);
}

// ---------------- prep: pack weights + fold BN/emb ----------------
__global__ __launch_bounds__(256)
void prep_kernel(const float* __restrict__ W1, const float* __restrict__ W2,
                 const float* __restrict__ bn_gamma, const float* __restrict__ bn_beta,
                 const float* __restrict__ bn_mean, const float* __restrict__ bn_var,
                 const float* __restrict__ emb, const int* __restrict__ etype,
                 ushort* __restrict__ B1p, ushort* __restrict__ B2p,
                 float* __restrict__ sc, float* __restrict__ sh)
{
    int i = blockIdx.x * blockDim.x + threadIdx.x;
    if (i < 65536) {
        // B1 frag: i = ((ks*8 + ct)*64 + lane)*8 + j ; k = ks*32+(lane>>4)*8+j ; c = ct*16+(lane&15)
        int j = i & 7, lane = (i >> 3) & 63, ct = (i >> 9) & 7, ks = i >> 12;
        int k = ks * 32 + (lane >> 4) * 8 + j;
        int c = ct * 16 + (lane & 15);
        B1p[i] = f2bf(W1[k * HID + c]);
    } else if (i < 65536 + 8192) {
        int p = i - 65536;
        int j = p & 7, lane = (p >> 3) & 63, ct = (p >> 9) & 3, ks = p >> 11;
        int k = ks * 32 + (lane >> 4) * 8 + j;
        int c = ct * 16 + (lane & 15);
        B2p[p] = f2bf(W2[k * 64 + c]);
    } else if (i < 65536 + 8192 + HID) {
        int c = i - 65536 - 8192;
        float s = bn_gamma[c] * rsqrtf(bn_var[c] + 1e-5f);
        sc[c] = s;
        sh[c] = bn_beta[c] - bn_mean[c] * s + emb[etype[0] * HID + c];
    }
}

// ---------------- proj: P = h @ W1_half  (dense, streaming) ----------------
// grid = 2*ntiles blocks; block b < ntiles -> src half, else dst half.
__global__ __launch_bounds__(256)
void proj_kernel(const float* __restrict__ h_src, const float* __restrict__ h_dst,
                 const ushort* __restrict__ B1p,
                 ushort* __restrict__ Psrc, ushort* __restrict__ Pdst,
                 int n_nodes, int ntiles)
{
    __shared__ ushort sX[ETILE * XS];

    const int b    = blockIdx.x;
    const int half = (b >= ntiles) ? 1 : 0;
    const float* hp = half ? h_dst : h_src;
    ushort* Pp      = half ? Pdst : Psrc;
    const int nb   = (b - half * ntiles) * 64;

    const int t    = threadIdx.x;
    const int lane = t & 63;
    const int w    = t >> 6;
    const int lr   = lane & 15;
    const int lq   = lane >> 4;

    f32x4 acc[4][2];
#pragma unroll
    for (int rt = 0; rt < 4; ++rt)
#pragma unroll
        for (int c = 0; c < 2; ++c) acc[rt][c] = (f32x4)0.0f;

    // K = 256 in 8 slices of 32; W1 rows offset by half*256 -> kstep = half*8+ksl
#pragma unroll
    for (int ksl = 0; ksl < 8; ++ksl) {
        const int kstep = half * 8 + ksl;
        bf16x8 bf0 = *reinterpret_cast<const bf16x8*>(
            B1p + (size_t)((kstep * 8 + 2 * w) * 64 + lane) * 8);
        bf16x8 bf1 = *reinterpret_cast<const bf16x8*>(
            B1p + (size_t)((kstep * 8 + 2 * w + 1) * 64 + lane) * 8);
#pragma unroll
        for (int rt = 0; rt < 4; ++rt) {
            int row = nb + rt * 16 + lr;
            if (row >= n_nodes) row = n_nodes - 1;     // tail clamp (writes guarded)
            const float* ap = hp + (size_t)row * 256 + ksl * 32 + lq * 8;
            float4 a0 = *reinterpret_cast<const float4*>(ap);
            float4 a1 = *reinterpret_cast<const float4*>(ap + 4);
            bf16x8 af;
            af[0] = (short)f2bf(a0.x); af[1] = (short)f2bf(a0.y);
            af[2] = (short)f2bf(a0.z); af[3] = (short)f2bf(a0.w);
            af[4] = (short)f2bf(a1.x); af[5] = (short)f2bf(a1.y);
            af[6] = (short)f2bf(a1.z); af[7] = (short)f2bf(a1.w);
            acc[rt][0] = __builtin_amdgcn_mfma_f32_16x16x32_bf16(af, bf0, acc[rt][0], 0, 0, 0);
            acc[rt][1] = __builtin_amdgcn_mfma_f32_16x16x32_bf16(af, bf1, acc[rt][1], 0, 0, 0);
        }
    }

    // acc -> LDS bf16 tile, then cooperative coalesced store to P
#pragma unroll
    for (int ctl = 0; ctl < 2; ++ctl) {
        int c = (2 * w + ctl) * 16 + lr;
#pragma unroll
        for (int rt = 0; rt < 4; ++rt)
#pragma unroll
            for (int r = 0; r < 4; ++r)
                sX[(rt * 16 + lq * 4 + r) * XS + c] = f2bf(acc[rt][ctl][r]);
    }
    __syncthreads();

#pragma unroll
    for (int i = 0; i < 4; ++i) {
        int f = t + i * 256;
        int e = f >> 4, q = f & 15;
        if (nb + e < n_nodes) {
            u16x8 v = *reinterpret_cast<const u16x8*>(&sX[e * XS + q * 8]);
            *reinterpret_cast<u16x8*>(Pp + (size_t)(nb + e) * 128 + q * 8) = v;
        }
    }
}

// ---------------- edge: gather P + add + ReLU/BN/emb + GEMM2/3 ----------------
__global__ __launch_bounds__(256)
void edge_kernel(const ushort* __restrict__ Psrc, const ushort* __restrict__ Pdst,
                 const int* __restrict__ src_nodes, const int* __restrict__ dst_nodes,
                 const float* __restrict__ b1, const float* __restrict__ sc,
                 const float* __restrict__ sh, const float* __restrict__ b2,
                 const float* __restrict__ W3, const float* __restrict__ b3,
                 const ushort* __restrict__ B2p, float* __restrict__ out, int n_edges)
{
    __shared__ ushort sX[ETILE * XS];
    __shared__ int s_s[ETILE], s_d[ETILE];

    const int t     = threadIdx.x;
    const int lane  = t & 63;
    const int w     = t >> 6;
    const int lr    = lane & 15;
    const int lq    = lane >> 4;
    const int ebase = blockIdx.x * ETILE;

    if (t < ETILE) {
        int e = ebase + t;
        s_s[t] = src_nodes[e < n_edges ? e : (n_edges - 1)];
    } else if (t < 2 * ETILE) {
        int e = ebase + t - ETILE;
        s_d[t - ETILE] = dst_nodes[e < n_edges ? e : (n_edges - 1)];
    }
    __syncthreads();

    // gather + fuse: 4 threads per edge, 32 channels each
    {
        const int e = t >> 2, q = t & 3;
        const ushort* ps = Psrc + (size_t)s_s[e] * 128 + q * 32;
        const ushort* pd = Pdst + (size_t)s_d[e] * 128 + q * 32;
#pragma unroll
        for (int j = 0; j < 4; ++j) {
            u16x8 a = *reinterpret_cast<const u16x8*>(ps + j * 8);
            u16x8 b = *reinterpret_cast<const u16x8*>(pd + j * 8);
            const int c0 = q * 32 + j * 8;
            float4 b1a = *reinterpret_cast<const float4*>(b1 + c0);
            float4 b1b = *reinterpret_cast<const float4*>(b1 + c0 + 4);
            float4 sca = *reinterpret_cast<const float4*>(sc + c0);
            float4 scb = *reinterpret_cast<const float4*>(sc + c0 + 4);
            float4 sha = *reinterpret_cast<const float4*>(sh + c0);
            float4 shb = *reinterpret_cast<const float4*>(sh + c0 + 4);
            float bb[8] = {b1a.x, b1a.y, b1a.z, b1a.w, b1b.x, b1b.y, b1b.z, b1b.w};
            float ss[8] = {sca.x, sca.y, sca.z, sca.w, scb.x, scb.y, scb.z, scb.w};
            float zz[8] = {sha.x, sha.y, sha.z, sha.w, shb.x, shb.y, shb.z, shb.w};
            u16x8 xo;
#pragma unroll
            for (int i = 0; i < 8; ++i) {
                float v = bf2f((ushort)a[i]) + bf2f((ushort)b[i]) + bb[i];
                v = fmaxf(v, 0.0f);
                xo[i] = f2bf(fmaf(v, ss[i], zz[i]));
            }
            *reinterpret_cast<u16x8*>(&sX[e * XS + c0]) = xo;
        }
    }
    __syncthreads();

    // -------- GEMM2: wave w owns rows [16w,16w+16), all 64 cols --------
    f32x4 acc2[4];
#pragma unroll
    for (int ct = 0; ct < 4; ++ct) acc2[ct] = (f32x4)0.0f;

#pragma unroll
    for (int ks = 0; ks < 4; ++ks) {
        bf16x8 af = *reinterpret_cast<const bf16x8*>(
            &sX[(w * 16 + lr) * XS + ks * 32 + lq * 8]);
#pragma unroll
        for (int ct = 0; ct < 4; ++ct) {
            bf16x8 bf = *reinterpret_cast<const bf16x8*>(
                B2p + (size_t)((ks * 4 + ct) * 64 + lane) * 8);
            acc2[ct] = __builtin_amdgcn_mfma_f32_16x16x32_bf16(af, bf, acc2[ct], 0, 0, 0);
        }
    }

    // -------- GEMM3: relu(y+b2) . W3 + b3, fp32, 16-lane shfl reduce --------
    float w3v[4], b2v[4];
#pragma unroll
    for (int ct = 0; ct < 4; ++ct) {
        int c = ct * 16 + lr;
        w3v[ct] = W3[c];
        b2v[ct] = b2[c];
    }
#pragma unroll
    for (int r = 0; r < 4; ++r) {
        float sum = 0.0f;
#pragma unroll
        for (int ct = 0; ct < 4; ++ct)
            sum += fmaxf(acc2[ct][r] + b2v[ct], 0.0f) * w3v[ct];
        sum += __shfl_xor(sum, 1);
        sum += __shfl_xor(sum, 2);
        sum += __shfl_xor(sum, 4);
        sum += __shfl_xor(sum, 8);
        int e = ebase + w * 16 + lq * 4 + r;
        if (lr == 0 && e < n_edges) out[e] = sum + b3[0];
    }
}

// ================= R4 fallback path (unchanged, known-good 97us) =================
__global__ __launch_bounds__(256, 4)
void edge_mlp_mfma(const float* __restrict__ h_src, const float* __restrict__ h_dst,
                   const int* __restrict__ src_nodes, const int* __restrict__ dst_nodes,
                   const ushort* __restrict__ B1p, const ushort* __restrict__ B2p,
                   const float* __restrict__ b1, const float* __restrict__ sc,
                   const float* __restrict__ sh, const float* __restrict__ b2,
                   const float* __restrict__ W3, const float* __restrict__ b3,
                   float* __restrict__ out, int n_edges)
{
    __shared__ ushort sA[2][ETILE * AS];
    __shared__ int s_src[ETILE], s_dst[ETILE];

    const int t    = threadIdx.x;
    const int lane = t & 63;
    const int w    = t >> 6;
    const int lr   = lane & 15;
    const int lq   = lane >> 4;
    const int ebase = blockIdx.x * ETILE;

    if (t < ETILE) {
        int e = ebase + t;
        s_src[t] = src_nodes[e < n_edges ? e : 0];
    } else if (t < 2 * ETILE) {
        int e = ebase + t - ETILE;
        s_dst[t - ETILE] = dst_nodes[e < n_edges ? e : 0];
    }

    f32x4 acc[4][2];
#pragma unroll
    for (int rt = 0; rt < 4; ++rt)
#pragma unroll
        for (int c = 0; c < 2; ++c) acc[rt][c] = (f32x4)0.0f;

    float4 rA[4], rB[4];
    bf16x8 Bf0[4], Bf1[4];

#define PHASE_BAR() do {                                                       \
        asm volatile("s_waitcnt lgkmcnt(0)" ::: "memory");                     \
        __builtin_amdgcn_s_barrier();                                          \
    } while (0)

#define LOADC(kc, R) do {                                                      \
        const float* hp = ((kc) < 4) ? h_src : h_dst;                          \
        const int* sidx = ((kc) < 4) ? s_src : s_dst;                          \
        const int koff = ((kc) & 3) * 64;                                      \
        _Pragma("unroll")                                                      \
        for (int i = 0; i < 4; ++i) {                                          \
            int f = t + i * 256; int e = f >> 4; int q = f & 15;               \
            R[i] = *reinterpret_cast<const float4*>(                           \
                hp + (size_t)sidx[e] * 256 + koff + q * 4);                    \
        } } while (0)

#define BLOAD(kc, BR) do {                                                     \
        _Pragma("unroll")                                                      \
        for (int s = 0; s < 2; ++s)                                            \
        _Pragma("unroll")                                                      \
        for (int c = 0; c < 2; ++c)                                            \
            BR[s * 2 + c] = *reinterpret_cast<const bf16x8*>(                  \
                B1p + (size_t)((((kc) * 2 + s) * 8 + 2 * w + c) * 64 + lane) * 8); \
        } while (0)

#define STOREC(B, R) do {                                                      \
        _Pragma("unroll")                                                      \
        for (int i = 0; i < 4; ++i) {                                          \
            int f = t + i * 256; int e = f >> 4; int q = f & 15;               \
            ushort4 bv;                                                        \
            bv.x = f2bf(R[i].x); bv.y = f2bf(R[i].y);                          \
            bv.z = f2bf(R[i].z); bv.w = f2bf(R[i].w);                          \
            *reinterpret_cast<ushort4*>(&sA[B][e * AS + q * 4]) = bv;          \
        } } while (0)

#define COMP(B, BR) do {                                                       \
        _Pragma("unroll")                                                      \
        for (int ks = 0; ks < 2; ++ks) {                                       \
            _Pragma("unroll")                                                  \
            for (int rt = 0; rt < 4; ++rt) {                                   \
                bf16x8 af = *reinterpret_cast<const bf16x8*>(                  \
                    &sA[B][(rt * 16 + lr) * AS + ks * 32 + lq * 8]);           \
                acc[rt][0] = __builtin_amdgcn_mfma_f32_16x16x32_bf16(af, BR[ks * 2 + 0], acc[rt][0], 0, 0, 0); \
                acc[rt][1] = __builtin_amdgcn_mfma_f32_16x16x32_bf16(af, BR[ks * 2 + 1], acc[rt][1], 0, 0, 0); \
            } } } while (0)

    __syncthreads();

    LOADC(0, rA);
    BLOAD(0, Bf0);
    STOREC(0, rA);
    LOADC(1, rB);
    BLOAD(1, Bf1);
    PHASE_BAR();

    LOADC(2, rA);  COMP(0, Bf0);  BLOAD(2, Bf0);  STOREC(1, rB);  PHASE_BAR();
    LOADC(3, rB);  COMP(1, Bf1);  BLOAD(3, Bf1);  STOREC(0, rA);  PHASE_BAR();
    LOADC(4, rA);  COMP(0, Bf0);  BLOAD(4, Bf0);  STOREC(1, rB);  PHASE_BAR();
    LOADC(5, rB);  COMP(1, Bf1);  BLOAD(5, Bf1);  STOREC(0, rA);  PHASE_BAR();
    LOADC(6, rA);  COMP(0, Bf0);  BLOAD(6, Bf0);  STOREC(1, rB);  PHASE_BAR();
    LOADC(7, rB);  COMP(1, Bf1);  BLOAD(7, Bf1);  STOREC(0, rA);  PHASE_BAR();
                   COMP(0, Bf0);                  STOREC(1, rB);  PHASE_BAR();
                   COMP(1, Bf1);

#undef LOADC
#undef BLOAD
#undef STOREC
#undef COMP
#undef PHASE_BAR

    __syncthreads();
    ushort* sX = &sA[0][0];
#pragma unroll
    for (int ctl = 0; ctl < 2; ++ctl) {
        int c = (2 * w + ctl) * 16 + lr;
        float bb = b1[c], s = sc[c], z = sh[c];
#pragma unroll
        for (int rt = 0; rt < 4; ++rt)
#pragma unroll
            for (int r = 0; r < 4; ++r) {
                float x = fmaxf(acc[rt][ctl][r] + bb, 0.0f);
                sX[(rt * 16 + lq * 4 + r) * XS + c] = f2bf(fmaf(x, s, z));
            }
    }
    __syncthreads();

    f32x4 acc2[4];
#pragma unroll
    for (int ct = 0; ct < 4; ++ct) acc2[ct] = (f32x4)0.0f;

#pragma unroll
    for (int ks = 0; ks < 4; ++ks) {
        bf16x8 af = *reinterpret_cast<const bf16x8*>(
            &sX[(w * 16 + lr) * XS + ks * 32 + lq * 8]);
#pragma unroll
        for (int ct = 0; ct < 4; ++ct) {
            bf16x8 bf = *reinterpret_cast<const bf16x8*>(
                B2p + (size_t)((ks * 4 + ct) * 64 + lane) * 8);
            acc2[ct] = __builtin_amdgcn_mfma_f32_16x16x32_bf16(af, bf, acc2[ct], 0, 0, 0);
        }
    }

    float w3v[4], b2v[4];
#pragma unroll
    for (int ct = 0; ct < 4; ++ct) {
        int c = ct * 16 + lr;
        w3v[ct] = W3[c];
        b2v[ct] = b2[c];
    }
#pragma unroll
    for (int r = 0; r < 4; ++r) {
        float sum = 0.0f;
#pragma unroll
        for (int ct = 0; ct < 4; ++ct)
            sum += fmaxf(acc2[ct][r] + b2v[ct], 0.0f) * w3v[ct];
        sum += __shfl_xor(sum, 1);
        sum += __shfl_xor(sum, 2);
        sum += __shfl_xor(sum, 4);
        sum += __shfl_xor(sum, 8);
        int e = ebase + w * 16 + lq * 4 + r;
        if (lr == 0 && e < n_edges) out[e] = sum + b3[0];
    }
}

extern "C" void kernel_launch(void* const* d_in, const int* in_sizes, int n_in,
                              void* d_out, int out_size, void* d_ws, size_t ws_size,
                              hipStream_t stream) {
    const float* h_src     = (const float*)d_in[0];
    const float* h_dst     = (const float*)d_in[1];
    const int*   src_nodes = (const int*)d_in[2];
    const int*   dst_nodes = (const int*)d_in[3];
    const int*   etype     = (const int*)d_in[4];
    const float* W1        = (const float*)d_in[5];
    const float* b1        = (const float*)d_in[6];
    const float* bn_gamma  = (const float*)d_in[7];
    const float* bn_beta   = (const float*)d_in[8];
    const float* bn_mean   = (const float*)d_in[9];
    const float* bn_var    = (const float*)d_in[10];
    const float* emb       = (const float*)d_in[11];
    const float* W2        = (const float*)d_in[12];
    const float* b2        = (const float*)d_in[13];
    const float* W3        = (const float*)d_in[14];
    const float* b3        = (const float*)d_in[15];

    const int n_edges = in_sizes[2];
    const int n_nodes = in_sizes[0] / 256;

    // d_ws layout: B1p[65536 u16] | B2p[8192 u16] | sc[128] | sh[128] | Psrc | Pdst
    ushort* B1p = (ushort*)d_ws;
    ushort* B2p = B1p + 65536;
    float*  scp = (float*)(B2p + 8192);
    float*  shp = scp + HID;
    const size_t wbytes = (size_t)(65536 + 8192) * 2 + 256 * 4;   // 148480 B
    const size_t pbytes = (size_t)n_nodes * HID * 2;              // per P array
    ushort* Psrc = (ushort*)((char*)d_ws + wbytes);
    ushort* Pdst = Psrc + (size_t)n_nodes * HID;

    prep_kernel<<<(65536 + 8192 + HID + 255) / 256, 256, 0, stream>>>(
        W1, W2, bn_gamma, bn_beta, bn_mean, bn_var, emb, etype, B1p, B2p, scp, shp);

    const int egrid = (n_edges + ETILE - 1) / ETILE;

    if (ws_size >= wbytes + 2 * pbytes) {
        // projection path
        const int ntiles = (n_nodes + 63) / 64;
        proj_kernel<<<2 * ntiles, 256, 0, stream>>>(h_src, h_dst, B1p,
                                                    Psrc, Pdst, n_nodes, ntiles);
        edge_kernel<<<egrid, 256, 0, stream>>>(Psrc, Pdst, src_nodes, dst_nodes,
                                               b1, scp, shp, b2, W3, b3, B2p,
                                               (float*)d_out, n_edges);
    } else {
        // fallback: R4 fused path
        edge_mlp_mfma<<<egrid, 256, 0, stream>>>(h_src, h_dst, src_nodes, dst_nodes,
                                                 B1p, B2p, b1, scp, shp, b2, W3, b3,
                                                 (float*)d_out, n_edges);
    }
}

// Round 9
// 169.705 us; speedup vs baseline: 1.0873x; 1.0873x over previous
//
#include <hip/hip_runtime.h>
#include <hip/hip_bf16.h>

// MultiEdgeTypePredictor — R6: projection path with deep load pipelining.
//
//   Psrc = h_src @ W1[:256,:] ; Pdst = h_dst @ W1[256:,:] + b1   (bf16, d_ws)
//   x[e] = relu(Psrc[s[e]] + Pdst[d[e]]) * sc + sh ; GEMM2 ; GEMM3
//
//   R6 vs R5: proj uses register double-buffer prefetch (loads for ksl+1
//   issued while computing ksl — 10 loads in flight/wave vs 2); edge hoists
//   all 8 gather loads before decode; b1 folded into Pdst.

typedef __attribute__((ext_vector_type(8))) short bf16x8;
typedef __attribute__((ext_vector_type(4))) float f32x4;
typedef __attribute__((ext_vector_type(8))) unsigned short u16x8;

constexpr int HID   = 128;
constexpr int ETILE = 64;
constexpr int AS    = 72;    // R4 chunk-buffer row stride (bf16 elems)
constexpr int XS    = 136;   // x-tile row stride (bf16 elems, 272B)

__device__ inline ushort f2bf(float f) {
    union { __hip_bfloat16 h; ushort u; } cv;
    cv.h = __float2bfloat16(f);   // RNE
    return cv.u;
}
__device__ inline float bf2f(ushort u) {
    return __uint_as_float(((unsigned int)u) << 16);
}

// ---------------- prep: pack weights + fold BN/emb ----------------
__global__ __launch_bounds__(256)
void prep_kernel(const float* __restrict__ W1, const float* __restrict__ W2,
                 const float* __restrict__ bn_gamma, const float* __restrict__ bn_beta,
                 const float* __restrict__ bn_mean, const float* __restrict__ bn_var,
                 const float* __restrict__ emb, const int* __restrict__ etype,
                 ushort* __restrict__ B1p, ushort* __restrict__ B2p,
                 float* __restrict__ sc, float* __restrict__ sh)
{
    int i = blockIdx.x * blockDim.x + threadIdx.x;
    if (i < 65536) {
        // B1 frag: i = ((ks*8 + ct)*64 + lane)*8 + j ; k = ks*32+(lane>>4)*8+j ; c = ct*16+(lane&15)
        int j = i & 7, lane = (i >> 3) & 63, ct = (i >> 9) & 7, ks = i >> 12;
        int k = ks * 32 + (lane >> 4) * 8 + j;
        int c = ct * 16 + (lane & 15);
        B1p[i] = f2bf(W1[k * HID + c]);
    } else if (i < 65536 + 8192) {
        int p = i - 65536;
        int j = p & 7, lane = (p >> 3) & 63, ct = (p >> 9) & 3, ks = p >> 11;
        int k = ks * 32 + (lane >> 4) * 8 + j;
        int c = ct * 16 + (lane & 15);
        B2p[p] = f2bf(W2[k * 64 + c]);
    } else if (i < 65536 + 8192 + HID) {
        int c = i - 65536 - 8192;
        float s = bn_gamma[c] * rsqrtf(bn_var[c] + 1e-5f);
        sc[c] = s;
        sh[c] = bn_beta[c] - bn_mean[c] * s + emb[etype[0] * HID + c];
    }
}

// ---------------- proj: P = h @ W1_half (+b1 on dst half), pipelined ----------
__global__ __launch_bounds__(256, 3)
void proj_kernel(const float* __restrict__ h_src, const float* __restrict__ h_dst,
                 const ushort* __restrict__ B1p, const float* __restrict__ b1,
                 ushort* __restrict__ Psrc, ushort* __restrict__ Pdst,
                 int n_nodes, int ntiles)
{
    __shared__ ushort sX[ETILE * XS];

    const int b    = blockIdx.x;
    const int half = (b >= ntiles) ? 1 : 0;
    const float* hp = half ? h_dst : h_src;
    ushort* Pp      = half ? Pdst : Psrc;
    const int nb   = (b - half * ntiles) * 64;

    const int t    = threadIdx.x;
    const int lane = t & 63;
    const int w    = t >> 6;
    const int lr   = lane & 15;
    const int lq   = lane >> 4;

    int rows[4];
#pragma unroll
    for (int rt = 0; rt < 4; ++rt) {
        int r = nb + rt * 16 + lr;
        rows[rt] = (r < n_nodes) ? r : (n_nodes - 1);   // tail clamp (stores guarded)
    }

    f32x4 acc[4][2];
#pragma unroll
    for (int rt = 0; rt < 4; ++rt)
#pragma unroll
        for (int c = 0; c < 2; ++c) acc[rt][c] = (f32x4)0.0f;

    float4 aA[8], aB[8];        // A double-buffer: [rt*2+pair]
    bf16x8 bA[2], bB[2];        // B-frag double-buffer

#define ALOAD(ksl, BUF) do {                                                   \
        _Pragma("unroll")                                                      \
        for (int rt = 0; rt < 4; ++rt) {                                       \
            const float* ap = hp + (size_t)rows[rt] * 256 + (ksl) * 32 + lq * 8; \
            BUF[rt * 2 + 0] = *reinterpret_cast<const float4*>(ap);            \
            BUF[rt * 2 + 1] = *reinterpret_cast<const float4*>(ap + 4);        \
        } } while (0)

#define BLOADP(ksl, BB) do {                                                   \
        const int kstep = half * 8 + (ksl);                                    \
        BB[0] = *reinterpret_cast<const bf16x8*>(                              \
            B1p + (size_t)((kstep * 8 + 2 * w) * 64 + lane) * 8);              \
        BB[1] = *reinterpret_cast<const bf16x8*>(                              \
            B1p + (size_t)((kstep * 8 + 2 * w + 1) * 64 + lane) * 8);          \
        } while (0)

#define PCOMP(BUF, BB) do {                                                    \
        _Pragma("unroll")                                                      \
        for (int rt = 0; rt < 4; ++rt) {                                       \
            bf16x8 af;                                                         \
            af[0] = (short)f2bf(BUF[rt*2].x);   af[1] = (short)f2bf(BUF[rt*2].y); \
            af[2] = (short)f2bf(BUF[rt*2].z);   af[3] = (short)f2bf(BUF[rt*2].w); \
            af[4] = (short)f2bf(BUF[rt*2+1].x); af[5] = (short)f2bf(BUF[rt*2+1].y); \
            af[6] = (short)f2bf(BUF[rt*2+1].z); af[7] = (short)f2bf(BUF[rt*2+1].w); \
            acc[rt][0] = __builtin_amdgcn_mfma_f32_16x16x32_bf16(af, BB[0], acc[rt][0], 0, 0, 0); \
            acc[rt][1] = __builtin_amdgcn_mfma_f32_16x16x32_bf16(af, BB[1], acc[rt][1], 0, 0, 0); \
        } } while (0)

    ALOAD(0, aA); BLOADP(0, bA);
    ALOAD(1, aB); BLOADP(1, bB);
    PCOMP(aA, bA);  ALOAD(2, aA); BLOADP(2, bA);
    PCOMP(aB, bB);  ALOAD(3, aB); BLOADP(3, bB);
    PCOMP(aA, bA);  ALOAD(4, aA); BLOADP(4, bA);
    PCOMP(aB, bB);  ALOAD(5, aB); BLOADP(5, bB);
    PCOMP(aA, bA);  ALOAD(6, aA); BLOADP(6, bA);
    PCOMP(aB, bB);  ALOAD(7, aB); BLOADP(7, bB);
    PCOMP(aA, bA);
    PCOMP(aB, bB);

#undef ALOAD
#undef BLOADP
#undef PCOMP

    // epilogue: fold b1 into the dst half; acc -> LDS bf16 tile
#pragma unroll
    for (int ctl = 0; ctl < 2; ++ctl) {
        int c = (2 * w + ctl) * 16 + lr;
        float add = half ? b1[c] : 0.0f;
#pragma unroll
        for (int rt = 0; rt < 4; ++rt)
#pragma unroll
            for (int r = 0; r < 4; ++r)
                sX[(rt * 16 + lq * 4 + r) * XS + c] = f2bf(acc[rt][ctl][r] + add);
    }
    __syncthreads();

    // cooperative coalesced store to P
#pragma unroll
    for (int i = 0; i < 4; ++i) {
        int f = t + i * 256;
        int e = f >> 4, q = f & 15;
        if (nb + e < n_nodes) {
            u16x8 v = *reinterpret_cast<const u16x8*>(&sX[e * XS + q * 8]);
            *reinterpret_cast<u16x8*>(Pp + (size_t)(nb + e) * 128 + q * 8) = v;
        }
    }
}

// ---------------- edge: hoisted gather + fuse + GEMM2/3 ----------------
__global__ __launch_bounds__(256, 4)
void edge_kernel(const ushort* __restrict__ Psrc, const ushort* __restrict__ Pdst,
                 const int* __restrict__ src_nodes, const int* __restrict__ dst_nodes,
                 const float* __restrict__ sc, const float* __restrict__ sh,
                 const float* __restrict__ b2, const float* __restrict__ W3,
                 const float* __restrict__ b3, const ushort* __restrict__ B2p,
                 float* __restrict__ out, int n_edges)
{
    __shared__ ushort sX[ETILE * XS];
    __shared__ int s_s[ETILE], s_d[ETILE];

    const int t     = threadIdx.x;
    const int lane  = t & 63;
    const int w     = t >> 6;
    const int lr    = lane & 15;
    const int lq    = lane >> 4;
    const int ebase = blockIdx.x * ETILE;

    if (t < ETILE) {
        int e = ebase + t;
        s_s[t] = src_nodes[e < n_edges ? e : (n_edges - 1)];
    } else if (t < 2 * ETILE) {
        int e = ebase + t - ETILE;
        s_d[t - ETILE] = dst_nodes[e < n_edges ? e : (n_edges - 1)];
    }
    __syncthreads();

    // gather: issue ALL 8 loads before any decode (8x16B in flight per thread)
    const int e = t >> 2, q = t & 3;
    const ushort* ps = Psrc + (size_t)s_s[e] * 128 + q * 32;
    const ushort* pd = Pdst + (size_t)s_d[e] * 128 + q * 32;
    u16x8 ga[4], gb[4];
#pragma unroll
    for (int j = 0; j < 4; ++j) ga[j] = *reinterpret_cast<const u16x8*>(ps + j * 8);
#pragma unroll
    for (int j = 0; j < 4; ++j) gb[j] = *reinterpret_cast<const u16x8*>(pd + j * 8);

    // decode: relu(a+b) * sc + sh -> x (bf16) in LDS
#pragma unroll
    for (int j = 0; j < 4; ++j) {
        const int c0 = q * 32 + j * 8;
        float4 sca = *reinterpret_cast<const float4*>(sc + c0);
        float4 scb = *reinterpret_cast<const float4*>(sc + c0 + 4);
        float4 sha = *reinterpret_cast<const float4*>(sh + c0);
        float4 shb = *reinterpret_cast<const float4*>(sh + c0 + 4);
        float ss[8] = {sca.x, sca.y, sca.z, sca.w, scb.x, scb.y, scb.z, scb.w};
        float zz[8] = {sha.x, sha.y, sha.z, sha.w, shb.x, shb.y, shb.z, shb.w};
        u16x8 xo;
#pragma unroll
        for (int i = 0; i < 8; ++i) {
            float v = bf2f((ushort)ga[j][i]) + bf2f((ushort)gb[j][i]);
            v = fmaxf(v, 0.0f);
            xo[i] = f2bf(fmaf(v, ss[i], zz[i]));
        }
        *reinterpret_cast<u16x8*>(&sX[e * XS + c0]) = xo;
    }
    __syncthreads();

    // -------- GEMM2: wave w owns rows [16w,16w+16), all 64 cols --------
    f32x4 acc2[4];
#pragma unroll
    for (int ct = 0; ct < 4; ++ct) acc2[ct] = (f32x4)0.0f;

#pragma unroll
    for (int ks = 0; ks < 4; ++ks) {
        bf16x8 af = *reinterpret_cast<const bf16x8*>(
            &sX[(w * 16 + lr) * XS + ks * 32 + lq * 8]);
#pragma unroll
        for (int ct = 0; ct < 4; ++ct) {
            bf16x8 bf = *reinterpret_cast<const bf16x8*>(
                B2p + (size_t)((ks * 4 + ct) * 64 + lane) * 8);
            acc2[ct] = __builtin_amdgcn_mfma_f32_16x16x32_bf16(af, bf, acc2[ct], 0, 0, 0);
        }
    }

    // -------- GEMM3: relu(y+b2) . W3 + b3, fp32, 16-lane shfl reduce --------
    float w3v[4], b2v[4];
#pragma unroll
    for (int ct = 0; ct < 4; ++ct) {
        int c = ct * 16 + lr;
        w3v[ct] = W3[c];
        b2v[ct] = b2[c];
    }
#pragma unroll
    for (int r = 0; r < 4; ++r) {
        float sum = 0.0f;
#pragma unroll
        for (int ct = 0; ct < 4; ++ct)
            sum += fmaxf(acc2[ct][r] + b2v[ct], 0.0f) * w3v[ct];
        sum += __shfl_xor(sum, 1);
        sum += __shfl_xor(sum, 2);
        sum += __shfl_xor(sum, 4);
        sum += __shfl_xor(sum, 8);
        int eo = ebase + w * 16 + lq * 4 + r;
        if (lr == 0 && eo < n_edges) out[eo] = sum + b3[0];
    }
}

// ================= R4 fallback path (known-good 97us) =================
__global__ __launch_bounds__(256, 4)
void edge_mlp_mfma(const float* __restrict__ h_src, const float* __restrict__ h_dst,
                   const int* __restrict__ src_nodes, const int* __restrict__ dst_nodes,
                   const ushort* __restrict__ B1p, const ushort* __restrict__ B2p,
                   const float* __restrict__ b1, const float* __restrict__ sc,
                   const float* __restrict__ sh, const float* __restrict__ b2,
                   const float* __restrict__ W3, const float* __restrict__ b3,
                   float* __restrict__ out, int n_edges)
{
    __shared__ ushort sA[2][ETILE * AS];
    __shared__ int s_src[ETILE], s_dst[ETILE];

    const int t    = threadIdx.x;
    const int lane = t & 63;
    const int w    = t >> 6;
    const int lr   = lane & 15;
    const int lq   = lane >> 4;
    const int ebase = blockIdx.x * ETILE;

    if (t < ETILE) {
        int e = ebase + t;
        s_src[t] = src_nodes[e < n_edges ? e : 0];
    } else if (t < 2 * ETILE) {
        int e = ebase + t - ETILE;
        s_dst[t - ETILE] = dst_nodes[e < n_edges ? e : 0];
    }

    f32x4 acc[4][2];
#pragma unroll
    for (int rt = 0; rt < 4; ++rt)
#pragma unroll
        for (int c = 0; c < 2; ++c) acc[rt][c] = (f32x4)0.0f;

    float4 rA[4], rB[4];
    bf16x8 Bf0[4], Bf1[4];

#define PHASE_BAR() do {                                                       \
        asm volatile("s_waitcnt lgkmcnt(0)" ::: "memory");                     \
        __builtin_amdgcn_s_barrier();                                          \
    } while (0)

#define LOADC(kc, R) do {                                                      \
        const float* hp = ((kc) < 4) ? h_src : h_dst;                          \
        const int* sidx = ((kc) < 4) ? s_src : s_dst;                          \
        const int koff = ((kc) & 3) * 64;                                      \
        _Pragma("unroll")                                                      \
        for (int i = 0; i < 4; ++i) {                                          \
            int f = t + i * 256; int e = f >> 4; int q = f & 15;               \
            R[i] = *reinterpret_cast<const float4*>(                           \
                hp + (size_t)sidx[e] * 256 + koff + q * 4);                    \
        } } while (0)

#define BLOAD(kc, BR) do {                                                     \
        _Pragma("unroll")                                                      \
        for (int s = 0; s < 2; ++s)                                            \
        _Pragma("unroll")                                                      \
        for (int c = 0; c < 2; ++c)                                            \
            BR[s * 2 + c] = *reinterpret_cast<const bf16x8*>(                  \
                B1p + (size_t)((((kc) * 2 + s) * 8 + 2 * w + c) * 64 + lane) * 8); \
        } while (0)

#define STOREC(B, R) do {                                                      \
        _Pragma("unroll")                                                      \
        for (int i = 0; i < 4; ++i) {                                          \
            int f = t + i * 256; int e = f >> 4; int q = f & 15;               \
            ushort4 bv;                                                        \
            bv.x = f2bf(R[i].x); bv.y = f2bf(R[i].y);                          \
            bv.z = f2bf(R[i].z); bv.w = f2bf(R[i].w);                          \
            *reinterpret_cast<ushort4*>(&sA[B][e * AS + q * 4]) = bv;          \
        } } while (0)

#define COMP(B, BR) do {                                                       \
        _Pragma("unroll")                                                      \
        for (int ks = 0; ks < 2; ++ks) {                                       \
            _Pragma("unroll")                                                  \
            for (int rt = 0; rt < 4; ++rt) {                                   \
                bf16x8 af = *reinterpret_cast<const bf16x8*>(                  \
                    &sA[B][(rt * 16 + lr) * AS + ks * 32 + lq * 8]);           \
                acc[rt][0] = __builtin_amdgcn_mfma_f32_16x16x32_bf16(af, BR[ks * 2 + 0], acc[rt][0], 0, 0, 0); \
                acc[rt][1] = __builtin_amdgcn_mfma_f32_16x16x32_bf16(af, BR[ks * 2 + 1], acc[rt][1], 0, 0, 0); \
            } } } while (0)

    __syncthreads();

    LOADC(0, rA);
    BLOAD(0, Bf0);
    STOREC(0, rA);
    LOADC(1, rB);
    BLOAD(1, Bf1);
    PHASE_BAR();

    LOADC(2, rA);  COMP(0, Bf0);  BLOAD(2, Bf0);  STOREC(1, rB);  PHASE_BAR();
    LOADC(3, rB);  COMP(1, Bf1);  BLOAD(3, Bf1);  STOREC(0, rA);  PHASE_BAR();
    LOADC(4, rA);  COMP(0, Bf0);  BLOAD(4, Bf0);  STOREC(1, rB);  PHASE_BAR();
    LOADC(5, rB);  COMP(1, Bf1);  BLOAD(5, Bf1);  STOREC(0, rA);  PHASE_BAR();
    LOADC(6, rA);  COMP(0, Bf0);  BLOAD(6, Bf0);  STOREC(1, rB);  PHASE_BAR();
    LOADC(7, rB);  COMP(1, Bf1);  BLOAD(7, Bf1);  STOREC(0, rA);  PHASE_BAR();
                   COMP(0, Bf0);                  STOREC(1, rB);  PHASE_BAR();
                   COMP(1, Bf1);

#undef LOADC
#undef BLOAD
#undef STOREC
#undef COMP
#undef PHASE_BAR

    __syncthreads();
    ushort* sX = &sA[0][0];
#pragma unroll
    for (int ctl = 0; ctl < 2; ++ctl) {
        int c = (2 * w + ctl) * 16 + lr;
        float bb = b1[c], s = sc[c], z = sh[c];
#pragma unroll
        for (int rt = 0; rt < 4; ++rt)
#pragma unroll
            for (int r = 0; r < 4; ++r) {
                float x = fmaxf(acc[rt][ctl][r] + bb, 0.0f);
                sX[(rt * 16 + lq * 4 + r) * XS + c] = f2bf(fmaf(x, s, z));
            }
    }
    __syncthreads();

    f32x4 acc2[4];
#pragma unroll
    for (int ct = 0; ct < 4; ++ct) acc2[ct] = (f32x4)0.0f;

#pragma unroll
    for (int ks = 0; ks < 4; ++ks) {
        bf16x8 af = *reinterpret_cast<const bf16x8*>(
            &sX[(w * 16 + lr) * XS + ks * 32 + lq * 8]);
#pragma unroll
        for (int ct = 0; ct < 4; ++ct) {
            bf16x8 bf = *reinterpret_cast<const bf16x8*>(
                B2p + (size_t)((ks * 4 + ct) * 64 + lane) * 8);
            acc2[ct] = __builtin_amdgcn_mfma_f32_16x16x32_bf16(af, bf, acc2[ct], 0, 0, 0);
        }
    }

    float w3v[4], b2v[4];
#pragma unroll
    for (int ct = 0; ct < 4; ++ct) {
        int c = ct * 16 + lr;
        w3v[ct] = W3[c];
        b2v[ct] = b2[c];
    }
#pragma unroll
    for (int r = 0; r < 4; ++r) {
        float sum = 0.0f;
#pragma unroll
        for (int ct = 0; ct < 4; ++ct)
            sum += fmaxf(acc2[ct][r] + b2v[ct], 0.0f) * w3v[ct];
        sum += __shfl_xor(sum, 1);
        sum += __shfl_xor(sum, 2);
        sum += __shfl_xor(sum, 4);
        sum += __shfl_xor(sum, 8);
        int e = ebase + w * 16 + lq * 4 + r;
        if (lr == 0 && e < n_edges) out[e] = sum + b3[0];
    }
}

extern "C" void kernel_launch(void* const* d_in, const int* in_sizes, int n_in,
                              void* d_out, int out_size, void* d_ws, size_t ws_size,
                              hipStream_t stream) {
    const float* h_src     = (const float*)d_in[0];
    const float* h_dst     = (const float*)d_in[1];
    const int*   src_nodes = (const int*)d_in[2];
    const int*   dst_nodes = (const int*)d_in[3];
    const int*   etype     = (const int*)d_in[4];
    const float* W1        = (const float*)d_in[5];
    const float* b1        = (const float*)d_in[6];
    const float* bn_gamma  = (const float*)d_in[7];
    const float* bn_beta   = (const float*)d_in[8];
    const float* bn_mean   = (const float*)d_in[9];
    const float* bn_var    = (const float*)d_in[10];
    const float* emb       = (const float*)d_in[11];
    const float* W2        = (const float*)d_in[12];
    const float* b2        = (const float*)d_in[13];
    const float* W3        = (const float*)d_in[14];
    const float* b3        = (const float*)d_in[15];

    const int n_edges = in_sizes[2];
    const int n_nodes = in_sizes[0] / 256;

    // d_ws layout: B1p[65536 u16] | B2p[8192 u16] | sc[128] | sh[128] | Psrc | Pdst
    ushort* B1p = (ushort*)d_ws;
    ushort* B2p = B1p + 65536;
    float*  scp = (float*)(B2p + 8192);
    float*  shp = scp + HID;
    const size_t wbytes = (size_t)(65536 + 8192) * 2 + 256 * 4;   // 148480 B
    const size_t pbytes = (size_t)n_nodes * HID * 2;              // per P array
    ushort* Psrc = (ushort*)((char*)d_ws + wbytes);
    ushort* Pdst = Psrc + (size_t)n_nodes * HID;

    prep_kernel<<<(65536 + 8192 + HID + 255) / 256, 256, 0, stream>>>(
        W1, W2, bn_gamma, bn_beta, bn_mean, bn_var, emb, etype, B1p, B2p, scp, shp);

    const int egrid = (n_edges + ETILE - 1) / ETILE;

    if (ws_size >= wbytes + 2 * pbytes) {
        const int ntiles = (n_nodes + 63) / 64;
        proj_kernel<<<2 * ntiles, 256, 0, stream>>>(h_src, h_dst, B1p, b1,
                                                    Psrc, Pdst, n_nodes, ntiles);
        edge_kernel<<<egrid, 256, 0, stream>>>(Psrc, Pdst, src_nodes, dst_nodes,
                                               scp, shp, b2, W3, b3, B2p,
                                               (float*)d_out, n_edges);
    } else {
        edge_mlp_mfma<<<egrid, 256, 0, stream>>>(h_src, h_dst, src_nodes, dst_nodes,
                                                 B1p, B2p, b1, scp, shp, b2, W3, b3,
                                                 (float*)d_out, n_edges);
    }
}

// Round 13
// 97.661 us; speedup vs baseline: 1.8894x; 1.7377x over previous
//
#include <hip/hip_runtime.h>
#include <hip/hip_bf16.h>

// MultiEdgeTypePredictor — R10: R9 minus the illegal KEEP asm (128-bit "v"
// constraints don't compile). PIN = sched_barrier(0) still pins gather issue
// at the top of each phase; completion waits happen naturally (counted vmcnt)
// at the next phase's STOREC — issue-early / wait-late with ~1.5 phases of
// latency budget. Diagnostic tell: VGPR_Count must rise to >=96 if the
// rA/rB/Bf0/Bf1 pipeline truly materializes (R4 showed 64 = impossible).

typedef __attribute__((ext_vector_type(8))) short bf16x8;
typedef __attribute__((ext_vector_type(4))) float f32x4;

constexpr int HID   = 128;
constexpr int ETILE = 64;
constexpr int AS    = 72;    // chunk-buffer row stride, bf16 elems (144 B)
constexpr int XS    = 136;   // x-tile row stride, bf16 elems (272 B)

__device__ inline ushort f2bf(float f) {
    union { __hip_bfloat16 h; ushort u; } cv;
    cv.h = __float2bfloat16(f);   // RNE
    return cv.u;
}

// ---------------- prep: pack weights + fold BN/emb ----------------
__global__ __launch_bounds__(256)
void prep_kernel(const float* __restrict__ W1, const float* __restrict__ W2,
                 const float* __restrict__ bn_gamma, const float* __restrict__ bn_beta,
                 const float* __restrict__ bn_mean, const float* __restrict__ bn_var,
                 const float* __restrict__ emb, const int* __restrict__ etype,
                 ushort* __restrict__ B1p, ushort* __restrict__ B2p,
                 float* __restrict__ sc, float* __restrict__ sh)
{
    int i = blockIdx.x * blockDim.x + threadIdx.x;
    if (i < 65536) {
        // B1 frag: i = ((ks*8 + ct)*64 + lane)*8 + j ; k = ks*32+(lane>>4)*8+j ; c = ct*16+(lane&15)
        int j = i & 7, lane = (i >> 3) & 63, ct = (i >> 9) & 7, ks = i >> 12;
        int k = ks * 32 + (lane >> 4) * 8 + j;
        int c = ct * 16 + (lane & 15);
        B1p[i] = f2bf(W1[k * HID + c]);
    } else if (i < 65536 + 8192) {
        int p = i - 65536;
        int j = p & 7, lane = (p >> 3) & 63, ct = (p >> 9) & 3, ks = p >> 11;
        int k = ks * 32 + (lane >> 4) * 8 + j;
        int c = ct * 16 + (lane & 15);
        B2p[p] = f2bf(W2[k * 64 + c]);
    } else if (i < 65536 + 8192 + HID) {
        int c = i - 65536 - 8192;
        float s = bn_gamma[c] * rsqrtf(bn_var[c] + 1e-5f);
        sc[c] = s;
        sh[c] = bn_beta[c] - bn_mean[c] * s + emb[etype[0] * HID + c];
    }
}

// ---------------- main fused kernel ----------------
__global__ __launch_bounds__(256, 3)
void edge_mlp_mfma(const float* __restrict__ h_src, const float* __restrict__ h_dst,
                   const int* __restrict__ src_nodes, const int* __restrict__ dst_nodes,
                   const ushort* __restrict__ B1p, const ushort* __restrict__ B2p,
                   const float* __restrict__ b1, const float* __restrict__ sc,
                   const float* __restrict__ sh, const float* __restrict__ b2,
                   const float* __restrict__ W3, const float* __restrict__ b3,
                   float* __restrict__ out, int n_edges)
{
    __shared__ ushort sA[2][ETILE * AS];     // 2 x 9216 B chunk buffers; later x-tile
    __shared__ int s_src[ETILE], s_dst[ETILE];

    const int t    = threadIdx.x;
    const int lane = t & 63;
    const int w    = t >> 6;          // wave 0..3
    const int lr   = lane & 15;
    const int lq   = lane >> 4;
    const int ebase = blockIdx.x * ETILE;

    if (t < ETILE) {
        int e = ebase + t;
        s_src[t] = src_nodes[e < n_edges ? e : 0];
    } else if (t < 2 * ETILE) {
        int e = ebase + t - ETILE;
        s_dst[t - ETILE] = dst_nodes[e < n_edges ? e : 0];
    }

    f32x4 acc[4][2];
#pragma unroll
    for (int rt = 0; rt < 4; ++rt)
#pragma unroll
        for (int c = 0; c < 2; ++c) acc[rt][c] = (f32x4)0.0f;

    float4 rA[4], rB[4];
    bf16x8 Bf0[4], Bf1[4];     // B1 fragment double-buffer: [ks][ct] flattened

    // barrier WITHOUT vmcnt drain: ds_writes visible, gathers stay in flight
#define PHASE_BAR() do {                                                       \
        asm volatile("s_waitcnt lgkmcnt(0)" ::: "memory");                     \
        __builtin_amdgcn_s_barrier();                                          \
    } while (0)

    // pin: loads issued above cannot sink below; later ops cannot hoist above
#define PIN() __builtin_amdgcn_sched_barrier(0)

    // chunk kc covers global k in [kc*64, kc*64+64): src for kc<4, dst for kc>=4
#define LOADC(kc, R) do {                                                      \
        const float* hp = ((kc) < 4) ? h_src : h_dst;                          \
        const int* sidx = ((kc) < 4) ? s_src : s_dst;                          \
        const int koff = ((kc) & 3) * 64;                                      \
        _Pragma("unroll")                                                      \
        for (int i = 0; i < 4; ++i) {                                          \
            int f = t + i * 256; int e = f >> 4; int q = f & 15;               \
            R[i] = *reinterpret_cast<const float4*>(                           \
                hp + (size_t)sidx[e] * 256 + koff + q * 4);                    \
        } } while (0)

#define BLOAD(kc, BR) do {                                                     \
        _Pragma("unroll")                                                      \
        for (int s = 0; s < 2; ++s)                                            \
        _Pragma("unroll")                                                      \
        for (int c = 0; c < 2; ++c)                                            \
            BR[s * 2 + c] = *reinterpret_cast<const bf16x8*>(                  \
                B1p + (size_t)((((kc) * 2 + s) * 8 + 2 * w + c) * 64 + lane) * 8); \
        } while (0)

#define STOREC(B, R) do {                                                      \
        _Pragma("unroll")                                                      \
        for (int i = 0; i < 4; ++i) {                                          \
            int f = t + i * 256; int e = f >> 4; int q = f & 15;               \
            ushort4 bv;                                                        \
            bv.x = f2bf(R[i].x); bv.y = f2bf(R[i].y);                          \
            bv.z = f2bf(R[i].z); bv.w = f2bf(R[i].w);                          \
            *reinterpret_cast<ushort4*>(&sA[B][e * AS + q * 4]) = bv;          \
        } } while (0)

#define COMP(B, BR) do {                                                       \
        _Pragma("unroll")                                                      \
        for (int ks = 0; ks < 2; ++ks) {                                       \
            _Pragma("unroll")                                                  \
            for (int rt = 0; rt < 4; ++rt) {                                   \
                bf16x8 af = *reinterpret_cast<const bf16x8*>(                  \
                    &sA[B][(rt * 16 + lr) * AS + ks * 32 + lq * 8]);           \
                acc[rt][0] = __builtin_amdgcn_mfma_f32_16x16x32_bf16(af, BR[ks * 2 + 0], acc[rt][0], 0, 0, 0); \
                acc[rt][1] = __builtin_amdgcn_mfma_f32_16x16x32_bf16(af, BR[ks * 2 + 1], acc[rt][1], 0, 0, 0); \
            } } } while (0)

    __syncthreads();                 // indices ready (full sync OK: no prefetch yet)

    // prologue
    LOADC(0, rA);
    BLOAD(0, Bf0);
    STOREC(0, rA);                   // waits gathers(0): unavoidable startup cost
    LOADC(1, rB);
    BLOAD(1, Bf1);
    PHASE_BAR();                     // buf0 ready; gathers(1) still in flight

    // steady state: pinned issue first; wait for prev gathers lands at STOREC
    LOADC(2, rA);  PIN();  COMP(0, Bf0);  BLOAD(2, Bf0);  STOREC(1, rB);  PHASE_BAR();
    LOADC(3, rB);  PIN();  COMP(1, Bf1);  BLOAD(3, Bf1);  STOREC(0, rA);  PHASE_BAR();
    LOADC(4, rA);  PIN();  COMP(0, Bf0);  BLOAD(4, Bf0);  STOREC(1, rB);  PHASE_BAR();
    LOADC(5, rB);  PIN();  COMP(1, Bf1);  BLOAD(5, Bf1);  STOREC(0, rA);  PHASE_BAR();
    LOADC(6, rA);  PIN();  COMP(0, Bf0);  BLOAD(6, Bf0);  STOREC(1, rB);  PHASE_BAR();
    LOADC(7, rB);  PIN();  COMP(1, Bf1);  BLOAD(7, Bf1);  STOREC(0, rA);  PHASE_BAR();
                           COMP(0, Bf0);                  STOREC(1, rB);  PHASE_BAR();
                           COMP(1, Bf1);

#undef LOADC
#undef BLOAD
#undef STOREC
#undef COMP
#undef PIN
#undef PHASE_BAR

    // -------- epilogue1: bias+relu+BN+emb -> x-tile (bf16, flat over sA) -----
    __syncthreads();                 // all COMP readers done (full drain fine here)
    ushort* sX = &sA[0][0];          // 64 x XS(136) = 8704 ushorts <= 9216 avail
#pragma unroll
    for (int ctl = 0; ctl < 2; ++ctl) {
        int c = (2 * w + ctl) * 16 + lr;
        float bb = b1[c], s = sc[c], z = sh[c];
#pragma unroll
        for (int rt = 0; rt < 4; ++rt)
#pragma unroll
            for (int r = 0; r < 4; ++r) {
                float x = fmaxf(acc[rt][ctl][r] + bb, 0.0f);
                sX[(rt * 16 + lq * 4 + r) * XS + c] = f2bf(fmaf(x, s, z));
            }
    }
    __syncthreads();

    // -------- GEMM2: wave w owns rows [16w,16w+16), all 64 cols --------
    f32x4 acc2[4];
#pragma unroll
    for (int ct = 0; ct < 4; ++ct) acc2[ct] = (f32x4)0.0f;

#pragma unroll
    for (int ks = 0; ks < 4; ++ks) {
        bf16x8 af = *reinterpret_cast<const bf16x8*>(
            &sX[(w * 16 + lr) * XS + ks * 32 + lq * 8]);
#pragma unroll
        for (int ct = 0; ct < 4; ++ct) {
            bf16x8 bf = *reinterpret_cast<const bf16x8*>(
                B2p + (size_t)((ks * 4 + ct) * 64 + lane) * 8);
            acc2[ct] = __builtin_amdgcn_mfma_f32_16x16x32_bf16(af, bf, acc2[ct], 0, 0, 0);
        }
    }

    // -------- GEMM3: relu(y+b2) . W3 + b3, fp32, 16-lane shfl reduce --------
    float w3v[4], b2v[4];
#pragma unroll
    for (int ct = 0; ct < 4; ++ct) {
        int c = ct * 16 + lr;
        w3v[ct] = W3[c];
        b2v[ct] = b2[c];
    }
#pragma unroll
    for (int r = 0; r < 4; ++r) {
        float sum = 0.0f;
#pragma unroll
        for (int ct = 0; ct < 4; ++ct)
            sum += fmaxf(acc2[ct][r] + b2v[ct], 0.0f) * w3v[ct];
        sum += __shfl_xor(sum, 1);
        sum += __shfl_xor(sum, 2);
        sum += __shfl_xor(sum, 4);
        sum += __shfl_xor(sum, 8);
        int e = ebase + w * 16 + lq * 4 + r;
        if (lr == 0 && e < n_edges) out[e] = sum + b3[0];
    }
}

extern "C" void kernel_launch(void* const* d_in, const int* in_sizes, int n_in,
                              void* d_out, int out_size, void* d_ws, size_t ws_size,
                              hipStream_t stream) {
    const float* h_src     = (const float*)d_in[0];
    const float* h_dst     = (const float*)d_in[1];
    const int*   src_nodes = (const int*)d_in[2];
    const int*   dst_nodes = (const int*)d_in[3];
    const int*   etype     = (const int*)d_in[4];
    const float* W1        = (const float*)d_in[5];
    const float* b1        = (const float*)d_in[6];
    const float* bn_gamma  = (const float*)d_in[7];
    const float* bn_beta   = (const float*)d_in[8];
    const float* bn_mean   = (const float*)d_in[9];
    const float* bn_var    = (const float*)d_in[10];
    const float* emb       = (const float*)d_in[11];
    const float* W2        = (const float*)d_in[12];
    const float* b2        = (const float*)d_in[13];
    const float* W3        = (const float*)d_in[14];
    const float* b3        = (const float*)d_in[15];

    // d_ws layout: B1p[65536 u16] | B2p[8192 u16] | sc[128 f32] | sh[128 f32]
    ushort* B1p = (ushort*)d_ws;
    ushort* B2p = B1p + 65536;
    float*  scp = (float*)(B2p + 8192);
    float*  shp = scp + HID;

    prep_kernel<<<(65536 + 8192 + HID + 255) / 256, 256, 0, stream>>>(
        W1, W2, bn_gamma, bn_beta, bn_mean, bn_var, emb, etype, B1p, B2p, scp, shp);

    const int n_edges = in_sizes[2];
    const int grid = (n_edges + ETILE - 1) / ETILE;
    edge_mlp_mfma<<<grid, 256, 0, stream>>>(h_src, h_dst, src_nodes, dst_nodes,
                                            B1p, B2p, b1, scp, shp, b2, W3, b3,
                                            (float*)d_out, n_edges);
}

// Round 14
// 89.299 us; speedup vs baseline: 2.0663x; 1.0936x over previous
//
#include <hip/hip_runtime.h>
#include <hip/hip_bf16.h>

// MultiEdgeTypePredictor — R11: projection path, R2-style coalesced staging.
//
//   Psrc = h_src @ W1[:256,:] ; Pdst = h_dst @ W1[256:,:] + b1   (bf16, d_ws)
//   x[e] = relu(Psrc[s[e]] + Pdst[d[e]]) * sc + sh ; GEMM2 ; GEMM3
//
//   proj: per 64-node tile, stage rows to LDS with fully-coalesced float4
//   loads (consecutive lanes -> consecutive addresses, the validated R2
//   pattern), cvt to bf16, MFMA vs L2-hot B1 frags. No DMA, no reg pipelining.
//   edge: R8's coalesced row-gather (256B contiguous per row, 16 lanes/row).
//   Fallback: R10 champion fused kernel if ws too small for P (~51.3 MB).

typedef __attribute__((ext_vector_type(8))) short bf16x8;
typedef __attribute__((ext_vector_type(4))) float f32x4;
typedef __attribute__((ext_vector_type(8))) unsigned short u16x8;

constexpr int HID   = 128;
constexpr int ETILE = 64;
constexpr int AS    = 72;    // fallback chunk stride (bf16 elems)
constexpr int XS    = 136;   // tile row stride (bf16 elems, 272B)

__device__ inline ushort f2bf(float f) {
    union { __hip_bfloat16 h; ushort u; } cv;
    cv.h = __float2bfloat16(f);   // RNE
    return cv.u;
}
__device__ inline float bf2f(ushort u) {
    return __uint_as_float(((unsigned int)u) << 16);
}

// ---------------- prep: pack weights + fold BN/emb ----------------
__global__ __launch_bounds__(256)
void prep_kernel(const float* __restrict__ W1, const float* __restrict__ W2,
                 const float* __restrict__ bn_gamma, const float* __restrict__ bn_beta,
                 const float* __restrict__ bn_mean, const float* __restrict__ bn_var,
                 const float* __restrict__ emb, const int* __restrict__ etype,
                 ushort* __restrict__ B1p, ushort* __restrict__ B2p,
                 float* __restrict__ sc, float* __restrict__ sh)
{
    int i = blockIdx.x * blockDim.x + threadIdx.x;
    if (i < 65536) {
        // B1 frag: i = ((ks*8 + ct)*64 + lane)*8 + j ; k = ks*32+(lane>>4)*8+j ; c = ct*16+(lane&15)
        int j = i & 7, lane = (i >> 3) & 63, ct = (i >> 9) & 7, ks = i >> 12;
        int k = ks * 32 + (lane >> 4) * 8 + j;
        int c = ct * 16 + (lane & 15);
        B1p[i] = f2bf(W1[k * HID + c]);
    } else if (i < 65536 + 8192) {
        int p = i - 65536;
        int j = p & 7, lane = (p >> 3) & 63, ct = (p >> 9) & 3, ks = p >> 11;
        int k = ks * 32 + (lane >> 4) * 8 + j;
        int c = ct * 16 + (lane & 15);
        B2p[p] = f2bf(W2[k * 64 + c]);
    } else if (i < 65536 + 8192 + HID) {
        int c = i - 65536 - 8192;
        float s = bn_gamma[c] * rsqrtf(bn_var[c] + 1e-5f);
        sc[c] = s;
        sh[c] = bn_beta[c] - bn_mean[c] * s + emb[etype[0] * HID + c];
    }
}

// ---------------- proj: P = h @ W1_half (+b1 on dst half) ----------------
__global__ __launch_bounds__(256)
void proj_kernel(const float* __restrict__ h_src, const float* __restrict__ h_dst,
                 const ushort* __restrict__ B1p, const float* __restrict__ b1,
                 ushort* __restrict__ Psrc, ushort* __restrict__ Pdst,
                 int n_nodes, int ntiles)
{
    __shared__ ushort sA[ETILE * XS];     // 64 x 136 bf16 = 17408 B (A-chunk / X-tile)

    const int b    = blockIdx.x;
    const int half = (b >= ntiles) ? 1 : 0;
    const float* hp = half ? h_dst : h_src;
    ushort* Pp      = half ? Pdst : Psrc;
    const int nb   = (b - half * ntiles) * 64;

    const int t    = threadIdx.x;
    const int lane = t & 63;
    const int w    = t >> 6;
    const int lr   = lane & 15;
    const int lq   = lane >> 4;

    f32x4 acc[4][2];
#pragma unroll
    for (int rt = 0; rt < 4; ++rt)
#pragma unroll
        for (int c = 0; c < 2; ++c) acc[rt][c] = (f32x4)0.0f;

    // K = 256 in 2 chunks of 128 (R2-validated staging + fragment pattern)
    for (int kc = 0; kc < 2; ++kc) {
        const int koff = kc * 128;
        __syncthreads();   // previous chunk readers done

        // stage 64 rows x 128 cols: 2048 float4, coalesced (consecutive lanes
        // -> consecutive float4 within a row), fp32 -> bf16
#pragma unroll
        for (int i = 0; i < 8; ++i) {
            int f = t + i * 256;
            int e = f >> 5, q = f & 31;
            int row = nb + e;
            if (row >= n_nodes) row = n_nodes - 1;   // tail clamp (stores guarded)
            float4 v = *reinterpret_cast<const float4*>(
                hp + (size_t)row * 256 + koff + q * 4);
            ushort4 bv;
            bv.x = f2bf(v.x); bv.y = f2bf(v.y); bv.z = f2bf(v.z); bv.w = f2bf(v.w);
            *reinterpret_cast<ushort4*>(&sA[e * XS + q * 4]) = bv;
        }
        __syncthreads();

#pragma unroll
        for (int ks = 0; ks < 4; ++ks) {
            const int kstep = half * 8 + kc * 4 + ks;
            bf16x8 bf0 = *reinterpret_cast<const bf16x8*>(
                B1p + (size_t)((kstep * 8 + 2 * w) * 64 + lane) * 8);
            bf16x8 bf1 = *reinterpret_cast<const bf16x8*>(
                B1p + (size_t)((kstep * 8 + 2 * w + 1) * 64 + lane) * 8);
#pragma unroll
            for (int rt = 0; rt < 4; ++rt) {
                bf16x8 af = *reinterpret_cast<const bf16x8*>(
                    &sA[(rt * 16 + lr) * XS + ks * 32 + lq * 8]);
                acc[rt][0] = __builtin_amdgcn_mfma_f32_16x16x32_bf16(af, bf0, acc[rt][0], 0, 0, 0);
                acc[rt][1] = __builtin_amdgcn_mfma_f32_16x16x32_bf16(af, bf1, acc[rt][1], 0, 0, 0);
            }
        }
    }

    __syncthreads();   // all A readers done before X-tile overwrite

    // epilogue: fold b1 into the dst half; acc -> LDS bf16 tile
#pragma unroll
    for (int ctl = 0; ctl < 2; ++ctl) {
        int c = (2 * w + ctl) * 16 + lr;
        float add = half ? b1[c] : 0.0f;
#pragma unroll
        for (int rt = 0; rt < 4; ++rt)
#pragma unroll
            for (int r = 0; r < 4; ++r)
                sA[(rt * 16 + lq * 4 + r) * XS + c] = f2bf(acc[rt][ctl][r] + add);
    }
    __syncthreads();

    // cooperative coalesced store to P
#pragma unroll
    for (int i = 0; i < 4; ++i) {
        int f = t + i * 256;
        int e = f >> 4, q = f & 15;
        if (nb + e < n_nodes) {
            u16x8 v = *reinterpret_cast<const u16x8*>(&sA[e * XS + q * 8]);
            *reinterpret_cast<u16x8*>(Pp + (size_t)(nb + e) * 128 + q * 8) = v;
        }
    }
}

// ---------------- edge: coalesced gather + fuse + GEMM2/3 (R8 form) ----------
__global__ __launch_bounds__(256)
void edge_kernel(const ushort* __restrict__ Psrc, const ushort* __restrict__ Pdst,
                 const int* __restrict__ src_nodes, const int* __restrict__ dst_nodes,
                 const float* __restrict__ sc, const float* __restrict__ sh,
                 const float* __restrict__ b2, const float* __restrict__ W3,
                 const float* __restrict__ b3, const ushort* __restrict__ B2p,
                 float* __restrict__ out, int n_edges)
{
    __shared__ ushort sX[ETILE * XS];
    __shared__ int s_s[ETILE], s_d[ETILE];

    const int t     = threadIdx.x;
    const int lane  = t & 63;
    const int w     = t >> 6;
    const int lr    = lane & 15;
    const int lq    = lane >> 4;
    const int ebase = blockIdx.x * ETILE;

    if (t < ETILE) {
        int e = ebase + t;
        s_s[t] = src_nodes[e < n_edges ? e : (n_edges - 1)];
    } else if (t < 2 * ETILE) {
        int e = ebase + t - ETILE;
        s_d[t - ETILE] = dst_nodes[e < n_edges ? e : (n_edges - 1)];
    }
    __syncthreads();

    // gather: 16 lanes per P row (256B contiguous segments). lane handles,
    // per j, edge eg + j*4, channels ch*8..ch*8+7.
    const int eg = w * 16 + lq;      // local edge group base
    const int ch = lr;               // 16B chunk within row
    u16x8 gs[4], gd[4];
#pragma unroll
    for (int j = 0; j < 4; ++j)
        gs[j] = *reinterpret_cast<const u16x8*>(
            Psrc + (size_t)s_s[eg + j * 4] * 128 + ch * 8);
#pragma unroll
    for (int j = 0; j < 4; ++j)
        gd[j] = *reinterpret_cast<const u16x8*>(
            Pdst + (size_t)s_d[eg + j * 4] * 128 + ch * 8);
    // keep all 8 loads issued before decode
    asm volatile("" :: "v"(gs[0]), "v"(gs[1]), "v"(gs[2]), "v"(gs[3]),
                       "v"(gd[0]), "v"(gd[1]), "v"(gd[2]), "v"(gd[3]));

    // decode: relu(a+b) * sc + sh -> x (bf16) in LDS (same channels all j)
    const int c0 = ch * 8;
    float4 sca = *reinterpret_cast<const float4*>(sc + c0);
    float4 scb = *reinterpret_cast<const float4*>(sc + c0 + 4);
    float4 sha = *reinterpret_cast<const float4*>(sh + c0);
    float4 shb = *reinterpret_cast<const float4*>(sh + c0 + 4);
    float ss[8] = {sca.x, sca.y, sca.z, sca.w, scb.x, scb.y, scb.z, scb.w};
    float zz[8] = {sha.x, sha.y, sha.z, sha.w, shb.x, shb.y, shb.z, shb.w};
#pragma unroll
    for (int j = 0; j < 4; ++j) {
        u16x8 xo;
#pragma unroll
        for (int i = 0; i < 8; ++i) {
            float v = bf2f((ushort)gs[j][i]) + bf2f((ushort)gd[j][i]);
            v = fmaxf(v, 0.0f);
            xo[i] = f2bf(fmaf(v, ss[i], zz[i]));
        }
        *reinterpret_cast<u16x8*>(&sX[(eg + j * 4) * XS + c0]) = xo;
    }
    __syncthreads();

    // -------- GEMM2: wave w owns rows [16w,16w+16), all 64 cols --------
    f32x4 acc2[4];
#pragma unroll
    for (int ct = 0; ct < 4; ++ct) acc2[ct] = (f32x4)0.0f;

#pragma unroll
    for (int ks = 0; ks < 4; ++ks) {
        bf16x8 af = *reinterpret_cast<const bf16x8*>(
            &sX[(w * 16 + lr) * XS + ks * 32 + lq * 8]);
#pragma unroll
        for (int ct = 0; ct < 4; ++ct) {
            bf16x8 bf = *reinterpret_cast<const bf16x8*>(
                B2p + (size_t)((ks * 4 + ct) * 64 + lane) * 8);
            acc2[ct] = __builtin_amdgcn_mfma_f32_16x16x32_bf16(af, bf, acc2[ct], 0, 0, 0);
        }
    }

    // -------- GEMM3: relu(y+b2) . W3 + b3, fp32, 16-lane shfl reduce --------
    float w3v[4], b2v[4];
#pragma unroll
    for (int ct = 0; ct < 4; ++ct) {
        int c = ct * 16 + lr;
        w3v[ct] = W3[c];
        b2v[ct] = b2[c];
    }
#pragma unroll
    for (int r = 0; r < 4; ++r) {
        float sum = 0.0f;
#pragma unroll
        for (int ct = 0; ct < 4; ++ct)
            sum += fmaxf(acc2[ct][r] + b2v[ct], 0.0f) * w3v[ct];
        sum += __shfl_xor(sum, 1);
        sum += __shfl_xor(sum, 2);
        sum += __shfl_xor(sum, 4);
        sum += __shfl_xor(sum, 8);
        int eo = ebase + w * 16 + lq * 4 + r;
        if (lr == 0 && eo < n_edges) out[eo] = sum + b3[0];
    }
}

// ================= fallback: R10 champion fused path (97.7us) =================
__global__ __launch_bounds__(256, 3)
void edge_mlp_mfma(const float* __restrict__ h_src, const float* __restrict__ h_dst,
                   const int* __restrict__ src_nodes, const int* __restrict__ dst_nodes,
                   const ushort* __restrict__ B1p, const ushort* __restrict__ B2p,
                   const float* __restrict__ b1, const float* __restrict__ sc,
                   const float* __restrict__ sh, const float* __restrict__ b2,
                   const float* __restrict__ W3, const float* __restrict__ b3,
                   float* __restrict__ out, int n_edges)
{
    __shared__ ushort sA[2][ETILE * AS];
    __shared__ int s_src[ETILE], s_dst[ETILE];

    const int t    = threadIdx.x;
    const int lane = t & 63;
    const int w    = t >> 6;
    const int lr   = lane & 15;
    const int lq   = lane >> 4;
    const int ebase = blockIdx.x * ETILE;

    if (t < ETILE) {
        int e = ebase + t;
        s_src[t] = src_nodes[e < n_edges ? e : 0];
    } else if (t < 2 * ETILE) {
        int e = ebase + t - ETILE;
        s_dst[t - ETILE] = dst_nodes[e < n_edges ? e : 0];
    }

    f32x4 acc[4][2];
#pragma unroll
    for (int rt = 0; rt < 4; ++rt)
#pragma unroll
        for (int c = 0; c < 2; ++c) acc[rt][c] = (f32x4)0.0f;

    float4 rA[4], rB[4];
    bf16x8 Bf0[4], Bf1[4];

#define PHASE_BAR() do {                                                       \
        asm volatile("s_waitcnt lgkmcnt(0)" ::: "memory");                     \
        __builtin_amdgcn_s_barrier();                                          \
    } while (0)
#define PIN() __builtin_amdgcn_sched_barrier(0)

#define LOADC(kc, R) do {                                                      \
        const float* hp = ((kc) < 4) ? h_src : h_dst;                          \
        const int* sidx = ((kc) < 4) ? s_src : s_dst;                          \
        const int koff = ((kc) & 3) * 64;                                      \
        _Pragma("unroll")                                                      \
        for (int i = 0; i < 4; ++i) {                                          \
            int f = t + i * 256; int e = f >> 4; int q = f & 15;               \
            R[i] = *reinterpret_cast<const float4*>(                           \
                hp + (size_t)sidx[e] * 256 + koff + q * 4);                    \
        } } while (0)

#define BLOAD(kc, BR) do {                                                     \
        _Pragma("unroll")                                                      \
        for (int s = 0; s < 2; ++s)                                            \
        _Pragma("unroll")                                                      \
        for (int c = 0; c < 2; ++c)                                            \
            BR[s * 2 + c] = *reinterpret_cast<const bf16x8*>(                  \
                B1p + (size_t)((((kc) * 2 + s) * 8 + 2 * w + c) * 64 + lane) * 8); \
        } while (0)

#define STOREC(B, R) do {                                                      \
        _Pragma("unroll")                                                      \
        for (int i = 0; i < 4; ++i) {                                          \
            int f = t + i * 256; int e = f >> 4; int q = f & 15;               \
            ushort4 bv;                                                        \
            bv.x = f2bf(R[i].x); bv.y = f2bf(R[i].y);                          \
            bv.z = f2bf(R[i].z); bv.w = f2bf(R[i].w);                          \
            *reinterpret_cast<ushort4*>(&sA[B][e * AS + q * 4]) = bv;          \
        } } while (0)

#define COMPF(B, BR) do {                                                      \
        _Pragma("unroll")                                                      \
        for (int ks = 0; ks < 2; ++ks) {                                       \
            _Pragma("unroll")                                                  \
            for (int rt = 0; rt < 4; ++rt) {                                   \
                bf16x8 af = *reinterpret_cast<const bf16x8*>(                  \
                    &sA[B][(rt * 16 + lr) * AS + ks * 32 + lq * 8]);           \
                acc[rt][0] = __builtin_amdgcn_mfma_f32_16x16x32_bf16(af, BR[ks * 2 + 0], acc[rt][0], 0, 0, 0); \
                acc[rt][1] = __builtin_amdgcn_mfma_f32_16x16x32_bf16(af, BR[ks * 2 + 1], acc[rt][1], 0, 0, 0); \
            } } } while (0)

    __syncthreads();

    LOADC(0, rA);
    BLOAD(0, Bf0);
    STOREC(0, rA);
    LOADC(1, rB);
    BLOAD(1, Bf1);
    PHASE_BAR();

    LOADC(2, rA);  PIN();  COMPF(0, Bf0);  BLOAD(2, Bf0);  STOREC(1, rB);  PHASE_BAR();
    LOADC(3, rB);  PIN();  COMPF(1, Bf1);  BLOAD(3, Bf1);  STOREC(0, rA);  PHASE_BAR();
    LOADC(4, rA);  PIN();  COMPF(0, Bf0);  BLOAD(4, Bf0);  STOREC(1, rB);  PHASE_BAR();
    LOADC(5, rB);  PIN();  COMPF(1, Bf1);  BLOAD(5, Bf1);  STOREC(0, rA);  PHASE_BAR();
    LOADC(6, rA);  PIN();  COMPF(0, Bf0);  BLOAD(6, Bf0);  STOREC(1, rB);  PHASE_BAR();
    LOADC(7, rB);  PIN();  COMPF(1, Bf1);  BLOAD(7, Bf1);  STOREC(0, rA);  PHASE_BAR();
                           COMPF(0, Bf0);                  STOREC(1, rB);  PHASE_BAR();
                           COMPF(1, Bf1);

#undef LOADC
#undef BLOAD
#undef STOREC
#undef COMPF
#undef PIN
#undef PHASE_BAR

    __syncthreads();
    ushort* sX = &sA[0][0];
#pragma unroll
    for (int ctl = 0; ctl < 2; ++ctl) {
        int c = (2 * w + ctl) * 16 + lr;
        float bb = b1[c], s = sc[c], z = sh[c];
#pragma unroll
        for (int rt = 0; rt < 4; ++rt)
#pragma unroll
            for (int r = 0; r < 4; ++r) {
                float x = fmaxf(acc[rt][ctl][r] + bb, 0.0f);
                sX[(rt * 16 + lq * 4 + r) * XS + c] = f2bf(fmaf(x, s, z));
            }
    }
    __syncthreads();

    f32x4 acc2[4];
#pragma unroll
    for (int ct = 0; ct < 4; ++ct) acc2[ct] = (f32x4)0.0f;

#pragma unroll
    for (int ks = 0; ks < 4; ++ks) {
        bf16x8 af = *reinterpret_cast<const bf16x8*>(
            &sX[(w * 16 + lr) * XS + ks * 32 + lq * 8]);
#pragma unroll
        for (int ct = 0; ct < 4; ++ct) {
            bf16x8 bf = *reinterpret_cast<const bf16x8*>(
                B2p + (size_t)((ks * 4 + ct) * 64 + lane) * 8);
            acc2[ct] = __builtin_amdgcn_mfma_f32_16x16x32_bf16(af, bf, acc2[ct], 0, 0, 0);
        }
    }

    float w3v[4], b2v[4];
#pragma unroll
    for (int ct = 0; ct < 4; ++ct) {
        int c = ct * 16 + lr;
        w3v[ct] = W3[c];
        b2v[ct] = b2[c];
    }
#pragma unroll
    for (int r = 0; r < 4; ++r) {
        float sum = 0.0f;
#pragma unroll
        for (int ct = 0; ct < 4; ++ct)
            sum += fmaxf(acc2[ct][r] + b2v[ct], 0.0f) * w3v[ct];
        sum += __shfl_xor(sum, 1);
        sum += __shfl_xor(sum, 2);
        sum += __shfl_xor(sum, 4);
        sum += __shfl_xor(sum, 8);
        int e = ebase + w * 16 + lq * 4 + r;
        if (lr == 0 && e < n_edges) out[e] = sum + b3[0];
    }
}

extern "C" void kernel_launch(void* const* d_in, const int* in_sizes, int n_in,
                              void* d_out, int out_size, void* d_ws, size_t ws_size,
                              hipStream_t stream) {
    const float* h_src     = (const float*)d_in[0];
    const float* h_dst     = (const float*)d_in[1];
    const int*   src_nodes = (const int*)d_in[2];
    const int*   dst_nodes = (const int*)d_in[3];
    const int*   etype     = (const int*)d_in[4];
    const float* W1        = (const float*)d_in[5];
    const float* b1        = (const float*)d_in[6];
    const float* bn_gamma  = (const float*)d_in[7];
    const float* bn_beta   = (const float*)d_in[8];
    const float* bn_mean   = (const float*)d_in[9];
    const float* bn_var    = (const float*)d_in[10];
    const float* emb       = (const float*)d_in[11];
    const float* W2        = (const float*)d_in[12];
    const float* b2        = (const float*)d_in[13];
    const float* W3        = (const float*)d_in[14];
    const float* b3        = (const float*)d_in[15];

    const int n_edges = in_sizes[2];
    const int n_nodes = in_sizes[0] / 256;

    // d_ws layout: B1p[65536 u16] | B2p[8192 u16] | sc[128] | sh[128] | Psrc | Pdst
    ushort* B1p = (ushort*)d_ws;
    ushort* B2p = B1p + 65536;
    float*  scp = (float*)(B2p + 8192);
    float*  shp = scp + HID;
    const size_t wbytes = (size_t)(65536 + 8192) * 2 + 256 * 4;   // 148480 B
    const size_t pbytes = (size_t)n_nodes * HID * 2;              // per P array
    ushort* Psrc = (ushort*)((char*)d_ws + wbytes);
    ushort* Pdst = Psrc + (size_t)n_nodes * HID;

    prep_kernel<<<(65536 + 8192 + HID + 255) / 256, 256, 0, stream>>>(
        W1, W2, bn_gamma, bn_beta, bn_mean, bn_var, emb, etype, B1p, B2p, scp, shp);

    const int egrid = (n_edges + ETILE - 1) / ETILE;

    if (ws_size >= wbytes + 2 * pbytes) {
        const int ntiles = (n_nodes + 63) / 64;
        proj_kernel<<<2 * ntiles, 256, 0, stream>>>(h_src, h_dst, B1p, b1,
                                                    Psrc, Pdst, n_nodes, ntiles);
        edge_kernel<<<egrid, 256, 0, stream>>>(Psrc, Pdst, src_nodes, dst_nodes,
                                               scp, shp, b2, W3, b3, B2p,
                                               (float*)d_out, n_edges);
    } else {
        edge_mlp_mfma<<<egrid, 256, 0, stream>>>(h_src, h_dst, src_nodes, dst_nodes,
                                                 B1p, B2p, b1, scp, shp, b2, W3, b3,
                                                 (float*)d_out, n_edges);
    }
}